// Round 11
// baseline (333.172 us; speedup 1.0000x reference)
//
#include <hip/hip_runtime.h>
#include <hip/hip_cooperative_groups.h>
#include <hip/hip_bf16.h>
#include <math.h>

namespace cg = cooperative_groups;

// Shapes: B=1, M=2, L=256, D=256, D2=512, S=128.
// Row convention: r = t*512 + (m*256 + l), t in {0(x),1(mouth)}.

__device__ __forceinline__ float silu_f(float v) {
    return v / (1.f + __expf(-v));
}
__device__ __forceinline__ float softplus_f(float v) {
    return fmaxf(v, 0.f) + log1pf(__expf(-fabsf(v)));
}

// ---- 32x64-tile GEMM phase, executed by a 256-thread half-block ----
// LDS: AsB = [2][32][36] (2304 f), WsB = [2][32][68] (4352 f); 6656 f per half.
// NORM: rmsnorm the A row in-block (K must be 256). All threads of the block
// call this with the SAME nch so the internal __syncthreads stays uniform;
// inactive halves run a dummy job with stores suppressed.
__device__ void gemm_tile(const float* __restrict__ A0, const float* __restrict__ A1,
                          const float* __restrict__ nw, bool NORM,
                          const float* __restrict__ W, const float* __restrict__ bias,
                          float* __restrict__ O, int ldo, int act,
                          int rt, int ct, int K,
                          float* AsB, float* WsB, int t, bool active) {
    const int r0 = rt * 32, c0 = ct * 64;
    const int sr = t >> 3;                // 0..31
    const int sk = (t & 7) << 2;          // 0..28
    const int rowA = r0 + sr;
    const float* rowbase = (rowA < 512) ? (A0 + (size_t)rowA * K)
                                        : (A1 + (size_t)(rowA - 512) * K);
    float ascale = 1.f;
    if (NORM) {   // 8 lanes (t&7) cooperate on this row's sum(x^2); K==256
        float ssum = 0.f;
        const float* rp = rowbase + (t & 7) * 32;
#pragma unroll
        for (int q = 0; q < 8; ++q) {
            float4 v = *(const float4*)(rp + q * 4);
            ssum += v.x * v.x + v.y * v.y + v.z * v.z + v.w * v.w;
        }
        ssum += __shfl_xor(ssum, 1);
        ssum += __shfl_xor(ssum, 2);
        ssum += __shfl_xor(ssum, 4);
        ascale = 1.f / sqrtf(ssum + 1e-5f);
    }
    const float* Abase = rowbase + sk;
    const float* W1b = W + (size_t)(c0 + sr) * K + sk;
    const float* W2b = W + (size_t)(c0 + 32 + sr) * K + sk;
    float4 areg = *(const float4*)Abase;
    float4 w1   = *(const float4*)W1b;
    float4 w2   = *(const float4*)W2b;
    float4 nwreg = NORM ? *(const float4*)(nw + sk) : make_float4(0.f, 0.f, 0.f, 0.f);
    const int tr = (t >> 5) << 2;         // 0..28
    const int tc = (t & 31) << 1;         // 0..62
    float acc[4][2] = {};
    const int nch = K >> 5;
    for (int ch = 0; ch < nch; ++ch) {
        const int p = ch & 1;
        float4 a = areg;
        if (NORM) {
            a.x *= ascale * nwreg.x; a.y *= ascale * nwreg.y;
            a.z *= ascale * nwreg.z; a.w *= ascale * nwreg.w;
        }
        AsB[p * 1152 + (sk + 0) * 36 + sr] = a.x;
        AsB[p * 1152 + (sk + 1) * 36 + sr] = a.y;
        AsB[p * 1152 + (sk + 2) * 36 + sr] = a.z;
        AsB[p * 1152 + (sk + 3) * 36 + sr] = a.w;
        WsB[p * 2176 + (sk + 0) * 68 + sr] = w1.x;
        WsB[p * 2176 + (sk + 1) * 68 + sr] = w1.y;
        WsB[p * 2176 + (sk + 2) * 68 + sr] = w1.z;
        WsB[p * 2176 + (sk + 3) * 68 + sr] = w1.w;
        WsB[p * 2176 + (sk + 0) * 68 + sr + 32] = w2.x;
        WsB[p * 2176 + (sk + 1) * 68 + sr + 32] = w2.y;
        WsB[p * 2176 + (sk + 2) * 68 + sr + 32] = w2.z;
        WsB[p * 2176 + (sk + 3) * 68 + sr + 32] = w2.w;
        __syncthreads();
        if (ch + 1 < nch) {
            const int ko = (ch + 1) << 5;
            areg = *(const float4*)(Abase + ko);
            w1   = *(const float4*)(W1b + ko);
            w2   = *(const float4*)(W2b + ko);
            if (NORM) nwreg = *(const float4*)(nw + ko + sk);
        }
#pragma unroll
        for (int kk = 0; kk < 32; ++kk) {
            const float4 a4 = *(const float4*)&AsB[p * 1152 + kk * 36 + tr];
            const float2 wv = *(const float2*)&WsB[p * 2176 + kk * 68 + tc];
            acc[0][0] = fmaf(a4.x, wv.x, acc[0][0]); acc[0][1] = fmaf(a4.x, wv.y, acc[0][1]);
            acc[1][0] = fmaf(a4.y, wv.x, acc[1][0]); acc[1][1] = fmaf(a4.y, wv.y, acc[1][1]);
            acc[2][0] = fmaf(a4.z, wv.x, acc[2][0]); acc[2][1] = fmaf(a4.z, wv.y, acc[2][1]);
            acc[3][0] = fmaf(a4.w, wv.x, acc[3][0]); acc[3][1] = fmaf(a4.w, wv.y, acc[3][1]);
        }
        // no trailing barrier: next iter stores to the other buffer (safe)
    }
    if (active) {
        const float2 bv = *(const float2*)(bias + c0 + tc);
#pragma unroll
        for (int i = 0; i < 4; ++i) {
            float vx = acc[i][0] + bv.x, vy = acc[i][1] + bv.y;
            if (act == 1)      { vx = silu_f(vx);     vy = silu_f(vy); }
            else if (act == 2) { vx = softplus_f(vx); vy = softplus_f(vy); }
            *(float2*)(O + (size_t)(r0 + tr + i) * ldo + c0 + tc) = make_float2(vx, vy);
        }
    }
}

// ---- single cooperative kernel: 256 blocks x 512 threads, 4 phases ----
__global__ __launch_bounds__(512) void coop_k(
        const float* __restrict__ x, const float* __restrict__ mouth,
        const float* __restrict__ nw,
        const float* __restrict__ inpW, const float* __restrict__ inpb,
        const float* __restrict__ outW, const float* __restrict__ outb,
        const float* __restrict__ DW,   const float* __restrict__ Db,
        const float* __restrict__ convW, const float* __restrict__ convB,
        const float* __restrict__ fc1W, const float* __restrict__ fc1b,
        const float* __restrict__ fc2W, const float* __restrict__ fc2b,
        const float* __restrict__ A,
        float* xp, float* xc, float* res, float* Bm, float* out) {
    __shared__ float smem[13312];     // 53.2 KB: 2 GEMM halves (6656 f each); P4 reuses
    cg::grid_group grid = cg::this_grid();
    const int tid  = threadIdx.x;
    const int half = tid >> 8;        // 0,1
    const int t    = tid & 255;
    float* AsB = smem + half * 6656;
    float* WsB = AsB + 2304;

    // ---- P1: dual-norm GEMM. 384 jobs: [0,256) xp tiles, [256,384) res tiles ----
    {
        const int job = blockIdx.x * 2 + half;        // 0..511
        const bool active = job < 384;
        const int j = active ? job : 0;
        const bool isres = j >= 256;
        const int jj = isres ? j - 256 : j;
        gemm_tile(x, mouth, nw, true,
                  isres ? DW : inpW, isres ? Db : inpb,
                  isres ? res : xp, 512, isres ? 1 : 0,
                  jj >> 3, jj & 7, 256, AsB, WsB, t, active);
    }
    grid.sync();
    // ---- P2: xc = silu(conv3x3(xp) + cb); 4 elements per thread ----
    {
#pragma unroll
        for (int jj = 0; jj < 4; ++jj) {
            const int idx = jj * 131072 + blockIdx.x * 512 + tid;   // < 524288
            const int w = idx & 511;
            const int l = (idx >> 9) & 255;
            const int o = (idx >> 17) & 1;
            const int tt = idx >> 18;
            float acc = convB[o];
#pragma unroll
            for (int i = 0; i < 2; ++i) {
                const float* base = xp + (size_t)((tt * 2 + i) * 256) * 512;
#pragma unroll
                for (int dh = -1; dh <= 1; ++dh) {
                    int ll = l + dh;
                    if (ll < 0 || ll > 255) continue;
#pragma unroll
                    for (int dw = -1; dw <= 1; ++dw) {
                        int ww = w + dw;
                        if (ww < 0 || ww > 511) continue;
                        acc += base[(size_t)ll * 512 + ww]
                             * convW[((o * 2 + i) * 3 + (dh + 1)) * 3 + (dw + 1)];
                    }
                }
            }
            xc[idx] = silu_f(acc);
        }
    }
    grid.sync();
    // ---- P3: fc1/fc2 GEMM. 320 jobs: [0,256) fc1 (delta=xp), [256,320) fc2 (Bm) ----
    {
        const int job = blockIdx.x * 2 + half;
        const bool active = job < 320;
        const int j = active ? job : 0;
        const bool isfc2 = j >= 256;
        const int jj = isfc2 ? j - 256 : j;
        gemm_tile(xc, xc + (size_t)512 * 512, nullptr, false,
                  isfc2 ? fc2W : fc1W, isfc2 ? fc2b : fc1b,
                  isfc2 ? Bm : xp, isfc2 ? 128 : 512, isfc2 ? 0 : 2,
                  isfc2 ? (jj >> 1) : (jj >> 3), isfc2 ? (jj & 1) : (jj & 7),
                  512, AsB, WsB, t, active);
    }
    grid.sync();
    // ---- P4: ssm + silu + combine + out-GEMM (1 job per block; delta aliases xp) ----
    {
        float* Bms   = smem;          // [2][2][128]
        float* combs = smem + 512;    // [2][512]
        float* red   = smem + 1536;   // [8]
        const float* delta = xp;
        const int m  = blockIdx.x >> 7;            // 0..1
        const int l0 = (blockIdx.x & 127) << 1;    // 0,2,..,254
        {   // stage Bm rows + per-(t,lr) sum(Bm^2)
            const int g = tid >> 7;                // 0..3: t=g>>1, lr=g&1
            const int tt = g >> 1, lr = g & 1, n = tid & 127;
            const int rg = tt * 512 + m * 256 + l0 + lr;
            float bv = Bm[(size_t)rg * 128 + n];
            Bms[g * 128 + n] = bv;
            float sq = bv * bv;
            for (int off = 32; off; off >>= 1) sq += __shfl_xor(sq, off);
            if ((tid & 63) == 0) red[tid >> 6] = sq;
        }
        __syncthreads();
        {   // ssm for d = tid, all 4 (t,lr) combos
            const int d = tid;
            float s2[2][2];
#pragma unroll
            for (int g = 0; g < 4; ++g) s2[g >> 1][g & 1] = red[2 * g] + red[2 * g + 1];
            float dl[2][2], xcv[2][2], rsv[2];
#pragma unroll
            for (int tt = 0; tt < 2; ++tt)
#pragma unroll
                for (int lr = 0; lr < 2; ++lr) {
                    const size_t r = (size_t)(tt * 512 + m * 256 + l0 + lr);
                    dl[tt][lr]  = delta[r * 512 + d];
                    xcv[tt][lr] = xc[r * 512 + d];
                }
            rsv[0] = res[(size_t)(m * 256 + l0) * 512 + d];
            rsv[1] = res[(size_t)(m * 256 + l0 + 1) * 512 + d];
            float accs[2][2] = {};
            const float4* arow = (const float4*)(A + (size_t)d * 128);
            for (int k4 = 0; k4 < 32; ++k4) {
                float4 a4 = arow[k4];
                const int n = k4 * 4;
#pragma unroll
                for (int cmp = 0; cmp < 4; ++cmp) {
                    float a = (cmp == 0) ? a4.x : (cmp == 1) ? a4.y : (cmp == 2) ? a4.z : a4.w;
#pragma unroll
                    for (int tt = 0; tt < 2; ++tt)
#pragma unroll
                        for (int lr = 0; lr < 2; ++lr)
                            accs[tt][lr] += Bms[(tt * 2 + lr) * 128 + n + cmp]
                                          * __expf(dl[tt][lr] * a);
                }
            }
#pragma unroll
            for (int lr = 0; lr < 2; ++lr) {
                float sx = accs[0][lr] + xcv[0][lr] * dl[0][lr] * s2[0][lr];
                float sm = accs[1][lr] + xcv[1][lr] * dl[1][lr] * s2[1][lr];
                combs[lr * 512 + d] = (silu_f(sx) + silu_f(sm)) * rsv[lr];
            }
        }
        __syncthreads();
        {   // out: 16-lane-coalesced outW reads shared across both rows
            const int wv = tid >> 6, lane = tid & 63;
            const int j = lane & 15, cg_ = lane >> 4;
#pragma unroll
            for (int rnd = 0; rnd < 8; ++rnd) {
                const int c = wv * 32 + rnd * 4 + cg_;
                const float4* wrow = (const float4*)(outW + (size_t)c * 512);
                float a0 = 0.f, a1 = 0.f;
#pragma unroll
                for (int it = 0; it < 8; ++it) {
                    const int k = it * 64 + j * 4;
                    float4 w4 = wrow[it * 16 + j];
                    a0 += w4.x * combs[k] + w4.y * combs[k + 1]
                        + w4.z * combs[k + 2] + w4.w * combs[k + 3];
                    a1 += w4.x * combs[512 + k] + w4.y * combs[512 + k + 1]
                        + w4.z * combs[512 + k + 2] + w4.w * combs[512 + k + 3];
                }
                a0 += __shfl_xor(a0, 1); a0 += __shfl_xor(a0, 2);
                a0 += __shfl_xor(a0, 4); a0 += __shfl_xor(a0, 8);
                a1 += __shfl_xor(a1, 1); a1 += __shfl_xor(a1, 2);
                a1 += __shfl_xor(a1, 4); a1 += __shfl_xor(a1, 8);
                if (j == 0) {
                    const float b = outb[c];
                    out[(size_t)(m * 256 + l0)     * 256 + c] = a0 + b;
                    out[(size_t)(m * 256 + l0 + 1) * 256 + c] = a1 + b;
                }
            }
        }
    }
}

extern "C" void kernel_launch(void* const* d_in, const int* in_sizes, int n_in,
                              void* d_out, int out_size, void* d_ws, size_t ws_size,
                              hipStream_t stream) {
    const float* x      = (const float*)d_in[0];
    const float* mouth  = (const float*)d_in[1];
    const float* norm_w = (const float*)d_in[2];
    const float* inp_W  = (const float*)d_in[3];
    const float* inp_b  = (const float*)d_in[4];
    const float* out_W  = (const float*)d_in[5];
    const float* out_b  = (const float*)d_in[6];
    const float* Dlin_W = (const float*)d_in[7];
    const float* Dlin_b = (const float*)d_in[8];
    const float* conv_W = (const float*)d_in[9];
    const float* conv_b = (const float*)d_in[10];
    const float* fc1_W  = (const float*)d_in[11];
    const float* fc1_b  = (const float*)d_in[12];
    const float* fc2_W  = (const float*)d_in[13];
    const float* fc2_b  = (const float*)d_in[14];
    const float* A      = (const float*)d_in[15];

    float* ws  = (float*)d_ws;
    float* xp  = ws;                        // 1024*512 (reused as delta by P3/P4)
    float* xc  = xp + 1024 * 512;           // 1024*512
    float* res = xc + 1024 * 512;           // 512*512
    float* Bmb = res + 512 * 512;           // 1024*128
    float* out = (float*)d_out;

    void* args[] = {
        (void*)&x, (void*)&mouth, (void*)&norm_w,
        (void*)&inp_W, (void*)&inp_b, (void*)&out_W, (void*)&out_b,
        (void*)&Dlin_W, (void*)&Dlin_b, (void*)&conv_W, (void*)&conv_b,
        (void*)&fc1_W, (void*)&fc1_b, (void*)&fc2_W, (void*)&fc2_b,
        (void*)&A, (void*)&xp, (void*)&xc, (void*)&res, (void*)&Bmb, (void*)&out,
    };
    hipLaunchCooperativeKernel((const void*)coop_k, dim3(256), dim3(512),
                               args, 0, stream);
}

// Round 12
// 136.073 us; speedup vs baseline: 2.4485x; 2.4485x over previous
//
#include <hip/hip_runtime.h>
#include <hip/hip_bf16.h>
#include <math.h>

// Shapes: B=1, M=2, L=256, D=256, D2=512, S=128.
// Row convention: r = t*512 + (m*256 + l), t in {0(x),1(mouth)}.

#define D_   256
#define D2_  512
#define S_   128

typedef short  bf16x8 __attribute__((ext_vector_type(8)));
typedef short  bf16x4 __attribute__((ext_vector_type(4)));
typedef float  f32x4  __attribute__((ext_vector_type(4)));

__device__ __forceinline__ float silu_f(float v) {
    return v / (1.f + __expf(-v));
}
__device__ __forceinline__ float softplus_f(float v) {
    return fmaxf(v, 0.f) + log1pf(__expf(-fabsf(v)));
}
__device__ __forceinline__ short f2bf(float f) {
    __hip_bfloat16 h = __float2bfloat16(f);
    return reinterpret_cast<short&>(h);
}

// ---- MFMA dual-output GEMM: tile 32(M) x 64(N), 256 threads (4 waves), KC=32 ----
// blocks [0,n1): O1 = act1(A@W1^T + b1); blocks [n1,..): O2 = act2(A@W2^T + b2).
// NORM: A rows rmsnorm'ed in-block (K==256). A rows >= 512 come from A1.
// LDS tiles in bf16, row stride 56 (112B: 16B-aligned, ~2-way banks on b128 reads).
// Wave w: rows (w&1)*16..+15, cols (w>>1)*32..+31 (two 16x16 MFMA accumulators).
// mfma_f32_16x16x32_bf16 frags: lane l holds row/col (l&15), k = (l>>4)*8+j;
// C/D: col = lane&15, row = (lane>>4)*4 + reg  [m89-verified].
template<bool NORM, int ACT1, int ACT2>
__global__ __launch_bounds__(256) void gemm_mfma_k(
        const float* __restrict__ A0, const float* __restrict__ A1,
        const float* __restrict__ nw,
        const float* __restrict__ W1, const float* __restrict__ bias1,
        float* __restrict__ O1, int nct1, int ldo1, int n1,
        const float* __restrict__ W2, const float* __restrict__ bias2,
        float* __restrict__ O2, int nct2, int ldo2, int K) {
    __shared__ __align__(16) short a_lds[2][32 * 56];
    __shared__ __align__(16) short w_lds[2][64 * 56];
    const int b = blockIdx.x;
    const float *W, *bias; float* O; int ldo, act, rt, ct;
    if (b < n1) { W = W1; bias = bias1; O = O1; ldo = ldo1; act = ACT1; rt = b / nct1; ct = b % nct1; }
    else { int bb = b - n1; W = W2; bias = bias2; O = O2; ldo = ldo2; act = ACT2; rt = bb / nct2; ct = bb % nct2; }
    const int r0 = rt * 32, c0 = ct * 64;
    const int t = threadIdx.x;
    // staging indices
    const int sr = t >> 3, sk = (t & 7) << 2;     // A: 8 thr/row, 4 floats each
    const int wc = t >> 2, wk = (t & 3) << 3;     // W: 4 thr/col, 8 floats each
    const int rowA = r0 + sr;
    const float* rowbase = (rowA < 512) ? (A0 + (size_t)rowA * K)
                                        : (A1 + (size_t)(rowA - 512) * K);
    float ascale = 1.f;
    if (NORM) {   // K == 256: 8 lanes (t&7) cooperate on this row's sum(x^2)
        float ssum = 0.f;
        const float* rp = rowbase + (t & 7) * 32;
#pragma unroll
        for (int q = 0; q < 8; ++q) {
            float4 v = *(const float4*)(rp + q * 4);
            ssum += v.x * v.x + v.y * v.y + v.z * v.z + v.w * v.w;
        }
        ssum += __shfl_xor(ssum, 1);
        ssum += __shfl_xor(ssum, 2);
        ssum += __shfl_xor(ssum, 4);
        ascale = 1.f / sqrtf(ssum + 1e-5f);
    }
    const float* Ag = rowbase + sk;
    const float* Wg = W + (size_t)(c0 + wc) * K + wk;
    float4 areg  = *(const float4*)Ag;
    float4 wrega = *(const float4*)Wg;
    float4 wregb = *(const float4*)(Wg + 4);
    float4 nwreg = NORM ? *(const float4*)(nw + sk) : make_float4(0.f, 0.f, 0.f, 0.f);
    // compute indices
    const int wv = t >> 6, lane = t & 63;
    const int aoff  = ((wv & 1) * 16 + (lane & 15)) * 56 + (lane >> 4) * 8;
    const int boff0 = ((wv >> 1) * 32 + (lane & 15)) * 56 + (lane >> 4) * 8;
    const int boff1 = boff0 + 16 * 56;
    f32x4 acc0 = {0.f, 0.f, 0.f, 0.f};
    f32x4 acc1 = {0.f, 0.f, 0.f, 0.f};
    const int nch = K >> 5;
    for (int ch = 0; ch < nch; ++ch) {
        const int p = ch & 1;
        float4 a = areg;
        if (NORM) {
            a.x *= ascale * nwreg.x; a.y *= ascale * nwreg.y;
            a.z *= ascale * nwreg.z; a.w *= ascale * nwreg.w;
        }
        bf16x4 av; av[0] = f2bf(a.x); av[1] = f2bf(a.y); av[2] = f2bf(a.z); av[3] = f2bf(a.w);
        *(bf16x4*)&a_lds[p][sr * 56 + sk] = av;           // 8B store, aligned
        bf16x8 wv8;
        wv8[0] = f2bf(wrega.x); wv8[1] = f2bf(wrega.y); wv8[2] = f2bf(wrega.z); wv8[3] = f2bf(wrega.w);
        wv8[4] = f2bf(wregb.x); wv8[5] = f2bf(wregb.y); wv8[6] = f2bf(wregb.z); wv8[7] = f2bf(wregb.w);
        *(bf16x8*)&w_lds[p][wc * 56 + wk] = wv8;          // 16B store, aligned
        __syncthreads();
        if (ch + 1 < nch) {
            const int ko = (ch + 1) << 5;
            areg  = *(const float4*)(Ag + ko);
            wrega = *(const float4*)(Wg + ko);
            wregb = *(const float4*)(Wg + ko + 4);
            if (NORM) nwreg = *(const float4*)(nw + ko + sk);
        }
        bf16x8 af  = *(const bf16x8*)&a_lds[p][aoff];
        bf16x8 bf0 = *(const bf16x8*)&w_lds[p][boff0];
        bf16x8 bf1 = *(const bf16x8*)&w_lds[p][boff1];
        acc0 = __builtin_amdgcn_mfma_f32_16x16x32_bf16(af, bf0, acc0, 0, 0, 0);
        acc1 = __builtin_amdgcn_mfma_f32_16x16x32_bf16(af, bf1, acc1, 0, 0, 0);
        // no trailing barrier: next iter stores to the other buffer (safe)
    }
    // epilogue: row = (lane>>4)*4 + i, col = lane&15 within each 16x16 tile
    const int rowE = r0 + (wv & 1) * 16 + (lane >> 4) * 4;
    const int colE = c0 + (wv >> 1) * 32 + (lane & 15);
#pragma unroll
    for (int cb = 0; cb < 2; ++cb) {
        const f32x4 acc = cb ? acc1 : acc0;
        const int col = colE + cb * 16;
        const float bv = bias[col];
#pragma unroll
        for (int i = 0; i < 4; ++i) {
            float v = acc[i] + bv;
            if (act == 1)      v = silu_f(v);
            else if (act == 2) v = softplus_f(v);
            O[(size_t)(rowE + i) * ldo + col] = v;
        }
    }
}

// ---- 3x3 SAME conv over (C=2, H=256, W=512), + bias + silu; 4 outputs/thread ----
__global__ __launch_bounds__(256) void conv_silu_k(
        const float* __restrict__ xp, const float* __restrict__ cW,
        const float* __restrict__ cb, float* __restrict__ xc) {
    const int idx = blockIdx.x * 256 + threadIdx.x;   // < 131072
    const int w0 = (idx & 127) * 4;
    const int l  = (idx >> 7) & 255;
    const int o  = (idx >> 15) & 1;
    const int tt = idx >> 16;
    const float cbv = cb[o];
    float a[4] = {cbv, cbv, cbv, cbv};
#pragma unroll
    for (int ii = 0; ii < 2; ++ii) {
        const float* base = xp + (size_t)((tt * 2 + ii) * 256) * 512;
#pragma unroll
        for (int dh = -1; dh <= 1; ++dh) {
            const int ll = l + dh;
            if (ll < 0 || ll > 255) continue;
            const float* p = base + (size_t)ll * 512 + w0;
            float4 mid = *(const float4*)p;
            float vm1 = (w0 > 0)   ? p[-1] : 0.f;
            float vp4 = (w0 < 508) ? p[4]  : 0.f;
            const float v[6] = {vm1, mid.x, mid.y, mid.z, mid.w, vp4};
            const float* cwp = &cW[((o * 2 + ii) * 3 + (dh + 1)) * 3];
#pragma unroll
            for (int j = 0; j < 4; ++j)
                a[j] += v[j] * cwp[0] + v[j + 1] * cwp[1] + v[j + 2] * cwp[2];
        }
    }
    float4 r = make_float4(silu_f(a[0]), silu_f(a[1]), silu_f(a[2]), silu_f(a[3]));
    *(float4*)(xc + (size_t)idx * 4) = r;
}

// ---- K4: fused SSM + silu + combine + out-GEMM (unchanged from R10) ----
__global__ __launch_bounds__(512) void ssm_out_k(
        const float* __restrict__ xc, const float* __restrict__ delta,
        const float* __restrict__ Bm, const float* __restrict__ A,
        const float* __restrict__ res, const float* __restrict__ outW,
        const float* __restrict__ outb, float* __restrict__ out) {
    __shared__ float Bms[2][2][S_];    // [t][lr][n]
    __shared__ float combs[2][D2_];    // [lr][d]
    __shared__ float red[8];
    const int tid = threadIdx.x;
    const int m  = blockIdx.x >> 7;            // 0..1
    const int l0 = (blockIdx.x & 127) << 1;    // 0,2,..,254

    {   // stage Bm rows + per-(t,lr) sum(Bm^2)
        const int g = tid >> 7;                // 0..3: t=g>>1, lr=g&1
        const int tt = g >> 1, lr = g & 1, n = tid & 127;
        const int rg = tt * 512 + m * 256 + l0 + lr;
        float bv = Bm[(size_t)rg * S_ + n];
        Bms[tt][lr][n] = bv;
        float sq = bv * bv;
        for (int off = 32; off; off >>= 1) sq += __shfl_xor(sq, off);
        if ((tid & 63) == 0) red[tid >> 6] = sq;   // s2(t,lr)=red[2g]+red[2g+1]
    }
    __syncthreads();
    {   // ssm for d = tid, all 4 (t,lr) combos; A[d] row read once
        const int d = tid;
        float s2[2][2];
#pragma unroll
        for (int g = 0; g < 4; ++g) s2[g >> 1][g & 1] = red[2 * g] + red[2 * g + 1];
        float dl[2][2], xcv[2][2], rsv[2];
#pragma unroll
        for (int tt = 0; tt < 2; ++tt)
#pragma unroll
            for (int lr = 0; lr < 2; ++lr) {
                const size_t r = (size_t)(tt * 512 + m * 256 + l0 + lr);
                dl[tt][lr]  = delta[r * D2_ + d];
                xcv[tt][lr] = xc[r * D2_ + d];
            }
        rsv[0] = res[(size_t)(m * 256 + l0) * D2_ + d];
        rsv[1] = res[(size_t)(m * 256 + l0 + 1) * D2_ + d];
        float accs[2][2] = {};
        const float4* arow = (const float4*)(A + (size_t)d * S_);
        for (int k4 = 0; k4 < 32; ++k4) {
            float4 a4 = arow[k4];
            const int n = k4 * 4;
#pragma unroll
            for (int cmp = 0; cmp < 4; ++cmp) {
                float a = (cmp == 0) ? a4.x : (cmp == 1) ? a4.y : (cmp == 2) ? a4.z : a4.w;
#pragma unroll
                for (int tt = 0; tt < 2; ++tt)
#pragma unroll
                    for (int lr = 0; lr < 2; ++lr)
                        accs[tt][lr] += Bms[tt][lr][n + cmp] * __expf(dl[tt][lr] * a);
            }
        }
#pragma unroll
        for (int lr = 0; lr < 2; ++lr) {
            float sx = accs[0][lr] + xcv[0][lr] * dl[0][lr] * s2[0][lr];
            float sm = accs[1][lr] + xcv[1][lr] * dl[1][lr] * s2[1][lr];
            combs[lr][d] = (silu_f(sx) + silu_f(sm)) * rsv[lr];
        }
    }
    __syncthreads();
    {   // out: 16-lane-coalesced outW reads shared across both rows
        const int wv = tid >> 6, lane = tid & 63;
        const int j = lane & 15, cg = lane >> 4;
#pragma unroll
        for (int rnd = 0; rnd < 8; ++rnd) {
            const int c = wv * 32 + rnd * 4 + cg;
            const float4* wrow = (const float4*)(outW + (size_t)c * D2_);
            float a0 = 0.f, a1 = 0.f;
#pragma unroll
            for (int it = 0; it < 8; ++it) {
                const int k = it * 64 + j * 4;
                float4 w4 = wrow[it * 16 + j];
                a0 += w4.x * combs[0][k] + w4.y * combs[0][k + 1]
                    + w4.z * combs[0][k + 2] + w4.w * combs[0][k + 3];
                a1 += w4.x * combs[1][k] + w4.y * combs[1][k + 1]
                    + w4.z * combs[1][k + 2] + w4.w * combs[1][k + 3];
            }
            a0 += __shfl_xor(a0, 1); a0 += __shfl_xor(a0, 2);
            a0 += __shfl_xor(a0, 4); a0 += __shfl_xor(a0, 8);
            a1 += __shfl_xor(a1, 1); a1 += __shfl_xor(a1, 2);
            a1 += __shfl_xor(a1, 4); a1 += __shfl_xor(a1, 8);
            if (j == 0) {
                const float b = outb[c];
                out[(size_t)(m * 256 + l0)     * D_ + c] = a0 + b;
                out[(size_t)(m * 256 + l0 + 1) * D_ + c] = a1 + b;
            }
        }
    }
}

extern "C" void kernel_launch(void* const* d_in, const int* in_sizes, int n_in,
                              void* d_out, int out_size, void* d_ws, size_t ws_size,
                              hipStream_t stream) {
    const float* x      = (const float*)d_in[0];
    const float* mouth  = (const float*)d_in[1];
    const float* norm_w = (const float*)d_in[2];
    const float* inp_W  = (const float*)d_in[3];
    const float* inp_b  = (const float*)d_in[4];
    const float* out_W  = (const float*)d_in[5];
    const float* out_b  = (const float*)d_in[6];
    const float* Dlin_W = (const float*)d_in[7];
    const float* Dlin_b = (const float*)d_in[8];
    const float* conv_W = (const float*)d_in[9];
    const float* conv_b = (const float*)d_in[10];
    const float* fc1_W  = (const float*)d_in[11];
    const float* fc1_b  = (const float*)d_in[12];
    const float* fc2_W  = (const float*)d_in[13];
    const float* fc2_b  = (const float*)d_in[14];
    const float* A      = (const float*)d_in[15];

    float* ws    = (float*)d_ws;
    float* xp    = ws;                        // 1024*512
    float* xc    = xp + 1024 * 512;           // 1024*512
    float* res   = xc + 1024 * 512;           // 512*512
    float* Bmb   = res + 512 * 512;           // 1024*128
    float* delta = xp;                        // alias: xp dead after conv
    float* out   = (float*)d_out;

    // K1: in-block rmsnorm + dual MFMA GEMM:
    //   xp  = xn @ inp_W^T + inp_b      (1024x512 -> 256 jobs)
    //   res = silu(xn_x @ Dlin_W^T + b) (512x512  -> 128 jobs); total 384.
    gemm_mfma_k<true, 0, 1><<<384, 256, 0, stream>>>(
        x, mouth, norm_w,
        inp_W, inp_b, xp, 8, 512, 256,
        Dlin_W, Dlin_b, res, 8, 512, 256);
    // K2: xc = silu(conv3x3(xp) + cb)
    conv_silu_k<<<512, 256, 0, stream>>>(xp, conv_W, conv_b, xc);
    // K3: dual MFMA GEMM: delta = softplus(xc@fc1_W^T+b) (1024x512 -> 256 jobs),
    //     Bm = xc@fc2_W^T+b (1024x128 -> 64 jobs); total 320.
    gemm_mfma_k<false, 2, 0><<<320, 256, 0, stream>>>(
        xc, xc + (size_t)512 * 512, nullptr,
        fc1_W, fc1_b, delta, 8, 512, 256,
        fc2_W, fc2_b, Bmb, 2, 128, 512);
    // K4: ssm + combine + out GEMM (2 rows per block)
    ssm_out_k<<<256, 512, 0, stream>>>(xc, delta, Bmb, A, res,
                                       out_W, out_b, out);
}